// Round 6
// baseline (217.535 us; speedup 1.0000x reference)
//
#include <hip/hip_runtime.h>
#include <hip/hip_bf16.h>
#include <stdint.h>

// Problem constants
#define BB   4
#define SS   2048
#define DIN  1024
#define DOUT 1024
#define NH   16
#define HD   64
#define MROWS (BB * SS)   // 8192

typedef __bf16 bf16x8 __attribute__((ext_vector_type(8)));
typedef float  f32x4  __attribute__((ext_vector_type(4)));

__device__ __forceinline__ unsigned short f2bf(float f) {
  union { float f; uint32_t u; } v; v.f = f;
  uint32_t u = v.u;
  uint32_t r = (u + 0x7fffu + ((u >> 16) & 1u)) >> 16;
  return (unsigned short)r;
}

// v_cvt_pk_bf16_f32: lo -> low16, hi -> high16 (RNE)
__device__ __forceinline__ unsigned int cvt_pk_bf16(float lo, float hi) {
  unsigned int r;
  asm("v_cvt_pk_bf16_f32 %0, %1, %2" : "=v"(r) : "v"(lo), "v"(hi));
  return r;
}

#define GLOAD_LDS16(gsrc, ldst)                                                   \
  __builtin_amdgcn_global_load_lds(                                               \
      (const __attribute__((address_space(1))) void*)(gsrc),                      \
      (__attribute__((address_space(3))) void*)(ldst), 16, 0, 0)

// ---------------- conversion kernels ----------------

__global__ void cvt_x_kernel(const float* __restrict__ in,
                             unsigned short* __restrict__ out, int n4) {
  int i = blockIdx.x * blockDim.x + threadIdx.x;
  int stride = gridDim.x * blockDim.x;
  for (; i < n4; i += stride) {
    float4 f = ((const float4*)in)[i];
    ushort4 o;
    o.x = f2bf(f.x); o.y = f2bf(f.y); o.z = f2bf(f.z); o.w = f2bf(f.w);
    ((ushort4*)out)[i] = o;
  }
}

// transpose-convert: out[n][k] = bf16(W[k][n]), per blockIdx.z matrix
__global__ void cvt_w_t_kernel(const float* __restrict__ w0,
                               const float* __restrict__ w1,
                               const float* __restrict__ w2,
                               const float* __restrict__ w3,
                               unsigned short* __restrict__ out) {
  __shared__ float tile[32][33];
  const float* src = (blockIdx.z == 0) ? w0 : (blockIdx.z == 1) ? w1
                   : (blockIdx.z == 2) ? w2 : w3;
  unsigned short* dst = out + (size_t)blockIdx.z * (DIN * DOUT);
  int kb = blockIdx.x * 32, nb = blockIdx.y * 32;
  tile[threadIdx.y][threadIdx.x] = src[(size_t)(kb + threadIdx.y) * DOUT + nb + threadIdx.x];
  __syncthreads();
  dst[(size_t)(nb + threadIdx.y) * DIN + kb + threadIdx.x] = f2bf(tile[threadIdx.x][threadIdx.y]);
}

// ---------------- GEMM core: 256x256 tile, 8 waves, ring-3 LDS, counted vmcnt
// A: row-major [.,1024] bf16 (pre-offset to tile row 0)
// BT: row-major [.,1024] bf16 = B transposed (pre-offset to tile col 0)
// LDS (dynamic, 96 KB): A slots 0..2 at s*8192 elems (256 rows x 32 cols),
// B slots at 24576 + s*8192. Swizzle: stored chunk p at row r holds logical
// chunk p ^ ((r>>1)&3); global_load_lds dest stays linear, source pre-XOR'd.
// Pipeline: stage(t+2) issued during compute(t); end-of-iter waits
// s_waitcnt vmcnt(4) (tile t+1 = 4 oldest calls) -- never a full drain.
__device__ __forceinline__ void gemm256_core(const unsigned short* __restrict__ A,
                                             const unsigned short* __restrict__ BT,
                                             f32x4 (&acc)[8][4]) {
  extern __shared__ __align__(16) unsigned short smem[];
  const int tid  = threadIdx.x;
  const int lane = tid & 63;
  const int w = tid >> 6;               // 0..7
  const int wr = w >> 2, wc = w & 3;    // 2M x 4N wave grid
  const int g = lane >> 4, c = lane & 15;

#pragma unroll
  for (int mi = 0; mi < 8; mi++)
#pragma unroll
    for (int ni = 0; ni < 4; ni++)
      acc[mi][ni] = (f32x4){0.f, 0.f, 0.f, 0.f};

  // staging: round r covers rows [r*128, +128); thread -> row (tid>>2),
  // LDS chunk (tid&3); global chunk pre-swizzled: (tid&3) ^ ((tid>>3)&3)
  const int srow = tid >> 2;
  const int slc  = (tid & 3) ^ ((tid >> 3) & 3);
  const unsigned short* Ag0 = A  + (size_t)srow * 1024 + slc * 8;
  const unsigned short* Ag1 = A  + (size_t)(srow + 128) * 1024 + slc * 8;
  const unsigned short* Bg0 = BT + (size_t)srow * 1024 + slc * 8;
  const unsigned short* Bg1 = BT + (size_t)(srow + 128) * 1024 + slc * 8;
  const int d0 = w * 512 + lane * 8;    // wave-uniform base + lane*16B (linear)
  const int d1 = 4096 + d0;

#define STAGE256(kt, sA, sB) do {                                   \
    const int _k = (kt) * 32;                                       \
    GLOAD_LDS16(Ag0 + _k, (sA) + d0);                               \
    GLOAD_LDS16(Ag1 + _k, (sA) + d1);                               \
    GLOAD_LDS16(Bg0 + _k, (sB) + d0);                               \
    GLOAD_LDS16(Bg1 + _k, (sB) + d1);                               \
  } while (0)

  // fragment-read offsets: row-major [256][32] per slot; phys chunk = g ^ ((c>>1)&3)
  const int rsw = (c >> 1) & 3;
  int aoff[8], boff[4];
#pragma unroll
  for (int mi = 0; mi < 8; mi++)
    aoff[mi] = (wr * 128 + mi * 16 + c) * 32 + ((g ^ rsw) * 8);
#pragma unroll
  for (int ni = 0; ni < 4; ni++)
    boff[ni] = (wc * 64 + ni * 16 + c) * 32 + ((g ^ rsw) * 8);

  // prologue: stage tiles 0,1 into slots 0,1; wait tile 0 (4 oldest), align
  STAGE256(0, smem, smem + 24576);
  STAGE256(1, smem + 8192, smem + 32768);
  asm volatile("s_waitcnt vmcnt(4)" ::: "memory");
  __builtin_amdgcn_s_barrier();

  int s = 0;        // slot of tile t
  int s2 = 2;       // slot of tile t+2
#pragma unroll 1
  for (int t = 0; t < 32; ++t) {
    const unsigned short* As_ = smem + s * 8192;
    const unsigned short* Bs_ = smem + 24576 + s * 8192;
    bf16x8 a[8], b[4];
#pragma unroll
    for (int mi = 0; mi < 8; mi++) a[mi] = *(const bf16x8*)&As_[aoff[mi]];
#pragma unroll
    for (int ni = 0; ni < 4; ni++) b[ni] = *(const bf16x8*)&Bs_[boff[ni]];
    if (t + 2 < 32)
      STAGE256(t + 2, smem + s2 * 8192, smem + 24576 + s2 * 8192);
    asm volatile("s_waitcnt lgkmcnt(0)" ::: "memory");
    __builtin_amdgcn_sched_barrier(0);
    __builtin_amdgcn_s_setprio(1);
#pragma unroll
    for (int mi = 0; mi < 8; mi++)
#pragma unroll
      for (int ni = 0; ni < 4; ni++)
        acc[mi][ni] = __builtin_amdgcn_mfma_f32_16x16x32_bf16(a[mi], b[ni], acc[mi][ni], 0, 0, 0);
    __builtin_amdgcn_s_setprio(0);
    if (t < 31) {
      if (t < 30) asm volatile("s_waitcnt vmcnt(4)" ::: "memory");  // tile t+1 resident
      else        asm volatile("s_waitcnt vmcnt(0)" ::: "memory");  // drain last stage
      __builtin_amdgcn_s_barrier();
    }
    s = (s == 2) ? 0 : s + 1;
    s2 = (s2 == 2) ? 0 : s2 + 1;
  }
#undef STAGE256
}

// QKV projection. z=0: Q (scaled log2e/8) -> [b][h][s][hd]; z=1: K; z=2: V^T [b][h][hd][s]
__global__ __launch_bounds__(512, 1) void gemm_qkv_kernel(
    const unsigned short* __restrict__ xb, const unsigned short* __restrict__ wt,
    unsigned short* __restrict__ qs, unsigned short* __restrict__ kbuf,
    unsigned short* __restrict__ vt) {
  const int nT = blockIdx.x, mT = blockIdx.y, z = blockIdx.z;
  f32x4 acc[8][4];
  gemm256_core(xb + (size_t)mT * 256 * 1024,
               wt + (size_t)z * (DIN * DOUT) + (size_t)nT * 256 * 1024, acc);

  const int tid = threadIdx.x, lane = tid & 63, w = tid >> 6;
  const int wr = w >> 2, wc = w & 3;
  const int g = lane >> 4, c = lane & 15;
  const float scale = (z == 0) ? 0.18033688011112042f : 1.0f;  // (1/8)*log2(e)
  unsigned short* dstQK = (z == 0) ? qs : kbuf;
  const int h = nT * 4 + wc;          // n = nT*256 + wc*64 + ni*16 + c -> h, hd
#pragma unroll
  for (int mi = 0; mi < 8; mi++)
#pragma unroll
    for (int ni = 0; ni < 4; ni++) {
      int hd = ni * 16 + c;
#pragma unroll
      for (int jj = 0; jj < 4; jj++) {
        int m = mT * 256 + wr * 128 + mi * 16 + g * 4 + jj;
        int b = m >> 11, ss = m & 2047;
        unsigned short val = f2bf(acc[mi][ni][jj] * scale);
        if (z < 2)
          dstQK[(((size_t)(b * NH + h)) * SS + ss) * HD + hd] = val;
        else
          vt[(((size_t)(b * NH + h)) * HD + hd) * SS + ss] = val;
      }
    }
}

// Output projection: out = ctx @ Wp + bp (fp32 out)
__global__ __launch_bounds__(512, 1) void gemm_out_kernel(
    const unsigned short* __restrict__ ctx, const unsigned short* __restrict__ wtp,
    const float* __restrict__ bp, float* __restrict__ out) {
  const int nT = blockIdx.x, mT = blockIdx.y;
  f32x4 acc[8][4];
  gemm256_core(ctx + (size_t)mT * 256 * 1024, wtp + (size_t)nT * 256 * 1024, acc);

  const int tid = threadIdx.x, lane = tid & 63, w = tid >> 6;
  const int wr = w >> 2, wc = w & 3;
  const int g = lane >> 4, c = lane & 15;
#pragma unroll
  for (int mi = 0; mi < 8; mi++)
#pragma unroll
    for (int ni = 0; ni < 4; ni++) {
      int n = nT * 256 + wc * 64 + ni * 16 + c;
      float bias = bp[n];
#pragma unroll
      for (int jj = 0; jj < 4; jj++) {
        int m = mT * 256 + wr * 128 + mi * 16 + g * 4 + jj;
        out[(size_t)m * DOUT + n] = acc[mi][ni][jj] + bias;
      }
    }
}

// ---------------- flash attention: 8-wave LDS-shared, balanced pairing -------
// (unchanged from round 4/5 -- passed, ~55 us)
__global__ __launch_bounds__(512) void attn_kernel(
    const unsigned short* __restrict__ qs, const unsigned short* __restrict__ kbuf,
    const unsigned short* __restrict__ vt, unsigned short* __restrict__ ctx) {
  const int pairIdx = blockIdx.x, h = blockIdx.y, b = blockIdx.z;
  const int tid = threadIdx.x, lane = tid & 63, w = tid >> 6;
  const int g = lane >> 4, c = lane & 15;
  const size_t bh = (size_t)(b * NH + h);
  const unsigned short* Q = qs + bh * SS * HD;
  const unsigned short* K = kbuf + bh * SS * HD;
  const unsigned short* V = vt + bh * HD * SS;   // [hd][s]

  __shared__ __align__(16) unsigned short Klds[2][64 * 64];
  __shared__ __align__(16) unsigned short Vlds[2][64 * 64];

  const int srow = tid >> 3, scol = tid & 7;
  const int sK_w = ((srow & 3) << 1) | ((srow >> 4) & 1);
  const int sV_w = ((srow & 3) << 1) | ((srow >> 2) & 1);
  const int kdst = srow * 64 + ((scol ^ sK_w) * 8);
  const int vdst = srow * 64 + ((scol ^ sV_w) * 8);
  const unsigned short* Kg0 = K + (size_t)srow * HD + scol * 8;
  const unsigned short* Vg0 = V + (size_t)srow * SS + scol * 8;

  int kaoff[4][2], vaoff[4][2];
#pragma unroll
  for (int ni = 0; ni < 4; ni++) {
    int r = (c >> 2) * 16 + ni * 4 + (c & 3);
    int s = ((r & 3) << 1) | ((r >> 4) & 1);
#pragma unroll
    for (int kk = 0; kk < 2; kk++)
      kaoff[ni][kk] = r * 64 + (((kk * 4 + g) ^ s) * 8);
  }
#pragma unroll
  for (int nh = 0; nh < 4; nh++) {
    int r = nh * 16 + c;
    int s = ((r & 3) << 1) | ((r >> 2) & 1);
#pragma unroll
    for (int k2 = 0; k2 < 2; k2++)
      vaoff[nh][k2] = r * 64 + (((2 * g + k2) ^ s) * 8);
  }

#pragma unroll 1
  for (int seg = 0; seg < 2; ++seg) {
    const int qtB = (seg == 0) ? (3 - pairIdx + 4) : pairIdx;
    const int q0 = qtB * 256 + w * 32;
    const int nt = 4 * qtB + 4;
    const int ntw = q0 / 64 + 1;

    bf16x8 aq[2][2];
#pragma unroll
    for (int qf = 0; qf < 2; qf++)
#pragma unroll
      for (int kk = 0; kk < 2; kk++)
        aq[qf][kk] = *(const bf16x8*)&Q[(size_t)(q0 + qf * 16 + c) * HD + kk * 32 + g * 8];

    float m_run[2] = {-3.0e38f, -3.0e38f};
    float l_run[2] = {0.f, 0.f};
    f32x4 acc[2][4];
#pragma unroll
    for (int qf = 0; qf < 2; qf++)
#pragma unroll
      for (int nh = 0; nh < 4; nh++) acc[qf][nh] = (f32x4){0.f, 0.f, 0.f, 0.f};

    {
      uint4 k0 = *(const uint4*)Kg0;
      uint4 v0 = *(const uint4*)Vg0;
      __syncthreads();
      *(uint4*)&Klds[0][kdst] = k0;
      *(uint4*)&Vlds[0][vdst] = v0;
      __syncthreads();
    }
    int cur = 0;

#pragma unroll 1
    for (int t = 0; t < nt; ++t) {
      const bool more = (t + 1 < nt);
      uint4 knx, vnx;
      if (more) {
        knx = *(const uint4*)(Kg0 + (size_t)(t + 1) * 64 * HD);
        vnx = *(const uint4*)(Vg0 + (size_t)(t + 1) * 64);
      }
      if (t < ntw) {
        const unsigned short* Kl = Klds[cur];
        const unsigned short* Vl = Vlds[cur];
        bf16x8 ka[4][2], va[4][2];
#pragma unroll
        for (int ni = 0; ni < 4; ni++)
#pragma unroll
          for (int kk = 0; kk < 2; kk++)
            ka[ni][kk] = *(const bf16x8*)&Kl[kaoff[ni][kk]];
#pragma unroll
        for (int nh = 0; nh < 4; nh++)
#pragma unroll
          for (int k2 = 0; k2 < 2; k2++)
            va[nh][k2] = *(const bf16x8*)&Vl[vaoff[nh][k2]];

        f32x4 sv[2][4];
        __builtin_amdgcn_s_setprio(1);
#pragma unroll
        for (int qf = 0; qf < 2; qf++)
#pragma unroll
          for (int ni = 0; ni < 4; ni++) {
            f32x4 z = (f32x4){0.f, 0.f, 0.f, 0.f};
            z = __builtin_amdgcn_mfma_f32_16x16x32_bf16(ka[ni][0], aq[qf][0], z, 0, 0, 0);
            sv[qf][ni] = __builtin_amdgcn_mfma_f32_16x16x32_bf16(ka[ni][1], aq[qf][1], z, 0, 0, 0);
          }
        __builtin_amdgcn_s_setprio(0);

        if (t == ntw - 1) {
#pragma unroll
          for (int qf = 0; qf < 2; qf++) {
            int q = q0 + qf * 16 + c;
#pragma unroll
            for (int ni = 0; ni < 4; ni++)
#pragma unroll
              for (int jj = 0; jj < 4; jj++) {
                int kvv = t * 64 + g * 16 + ni * 4 + jj;
                if (kvv > q) sv[qf][ni][jj] = -3.0e38f;
              }
          }
        }

#pragma unroll
        for (int qf = 0; qf < 2; qf++) {
          float mx = sv[qf][0][0];
#pragma unroll
          for (int ni = 0; ni < 4; ni++)
#pragma unroll
            for (int jj = 0; jj < 4; jj++) mx = fmaxf(mx, sv[qf][ni][jj]);
          mx = fmaxf(mx, __shfl_xor(mx, 16));
          mx = fmaxf(mx, __shfl_xor(mx, 32));
          float mnew = fmaxf(m_run[qf], mx);
          float al = exp2f(m_run[qf] - mnew);
          m_run[qf] = mnew;
          float rs = 0.f;
#pragma unroll
          for (int ni = 0; ni < 4; ni++)
#pragma unroll
            for (int jj = 0; jj < 4; jj++) {
              float p = exp2f(sv[qf][ni][jj] - mnew);
              sv[qf][ni][jj] = p;
              rs += p;
            }
          rs += __shfl_xor(rs, 16);
          rs += __shfl_xor(rs, 32);
          l_run[qf] = l_run[qf] * al + rs;
#pragma unroll
          for (int nh = 0; nh < 4; nh++) acc[qf][nh] *= al;

          union { unsigned int u[4]; bf16x8 v; } pb0, pb1;
          pb0.u[0] = cvt_pk_bf16(sv[qf][0][0], sv[qf][0][1]);
          pb0.u[1] = cvt_pk_bf16(sv[qf][0][2], sv[qf][0][3]);
          pb0.u[2] = cvt_pk_bf16(sv[qf][1][0], sv[qf][1][1]);
          pb0.u[3] = cvt_pk_bf16(sv[qf][1][2], sv[qf][1][3]);
          pb1.u[0] = cvt_pk_bf16(sv[qf][2][0], sv[qf][2][1]);
          pb1.u[1] = cvt_pk_bf16(sv[qf][2][2], sv[qf][2][3]);
          pb1.u[2] = cvt_pk_bf16(sv[qf][3][0], sv[qf][3][1]);
          pb1.u[3] = cvt_pk_bf16(sv[qf][3][2], sv[qf][3][3]);

          __builtin_amdgcn_s_setprio(1);
#pragma unroll
          for (int nh = 0; nh < 4; nh++) {
            acc[qf][nh] = __builtin_amdgcn_mfma_f32_16x16x32_bf16(va[nh][0], pb0.v, acc[qf][nh], 0, 0, 0);
            acc[qf][nh] = __builtin_amdgcn_mfma_f32_16x16x32_bf16(va[nh][1], pb1.v, acc[qf][nh], 0, 0, 0);
          }
          __builtin_amdgcn_s_setprio(0);
        }
      }
      if (more) {
        *(uint4*)&Klds[cur ^ 1][kdst] = knx;
        *(uint4*)&Vlds[cur ^ 1][vdst] = vnx;
        __syncthreads();
        cur ^= 1;
      }
    }

#pragma unroll
    for (int qf = 0; qf < 2; qf++) {
      float inv = 1.0f / l_run[qf];
      size_t rowoff = ((size_t)b * SS + q0 + qf * 16 + c) * DOUT + h * HD;
#pragma unroll
      for (int nh = 0; nh < 4; nh++) {
        uint2 st;
        st.x = cvt_pk_bf16(acc[qf][nh][0] * inv, acc[qf][nh][1] * inv);
        st.y = cvt_pk_bf16(acc[qf][nh][2] * inv, acc[qf][nh][3] * inv);
        *(uint2*)&ctx[rowoff + nh * 16 + g * 4] = st;
      }
    }
  }
}

// ---------------- launch ----------------

extern "C" void kernel_launch(void* const* d_in, const int* in_sizes, int n_in,
                              void* d_out, int out_size, void* d_ws, size_t ws_size,
                              hipStream_t stream) {
  const float* x  = (const float*)d_in[0];
  const float* Wq = (const float*)d_in[1];
  const float* Wk = (const float*)d_in[2];
  const float* Wv = (const float*)d_in[3];
  const float* Wp = (const float*)d_in[4];
  const float* bp = (const float*)d_in[5];
  float* out = (float*)d_out;

  unsigned short* ws = (unsigned short*)d_ws;
  unsigned short* xb = ws;                      // 8388608 elems (x bf16; later reused as ctx)
  unsigned short* wt = xb + (size_t)MROWS * DIN;       // 4 * 1048576 (Wq^T,Wk^T,Wv^T,Wp^T)
  unsigned short* qs = wt + (size_t)4 * DIN * DOUT;    // 8388608 (Q scaled, [b][h][s][hd])
  unsigned short* kb = qs + (size_t)MROWS * DOUT;      // 8388608 ([b][h][s][hd])
  unsigned short* vt = kb + (size_t)MROWS * DOUT;      // 8388608 ([b][h][hd][s])
  unsigned short* ctx = xb;                            // alias: x dead after projections

  const int kLds = 96 * 1024;   // ring-3 LDS for the 256^2 GEMM cores
  (void)hipFuncSetAttribute((const void*)gemm_qkv_kernel,
                            hipFuncAttributeMaxDynamicSharedMemorySize, kLds);
  (void)hipFuncSetAttribute((const void*)gemm_out_kernel,
                            hipFuncAttributeMaxDynamicSharedMemorySize, kLds);

  cvt_x_kernel<<<4096, 256, 0, stream>>>(x, xb, (MROWS * DIN) / 4);
  cvt_w_t_kernel<<<dim3(32, 32, 4), dim3(32, 32), 0, stream>>>(Wq, Wk, Wv, Wp, wt);
  gemm_qkv_kernel<<<dim3(4, 32, 3), 512, kLds, stream>>>(xb, wt, qs, kb, vt);
  attn_kernel<<<dim3(4, NH, BB), 512, 0, stream>>>(qs, kb, vt, ctx);
  gemm_out_kernel<<<dim3(4, 32), 512, kLds, stream>>>(ctx, wt + (size_t)3 * DIN * DOUT, bp, out);
}

// Round 7
// 210.442 us; speedup vs baseline: 1.0337x; 1.0337x over previous
//
#include <hip/hip_runtime.h>
#include <hip/hip_bf16.h>
#include <stdint.h>

// Problem constants
#define BB   4
#define SS   2048
#define DIN  1024
#define DOUT 1024
#define NH   16
#define HD   64
#define MROWS (BB * SS)   // 8192

typedef __bf16 bf16x8 __attribute__((ext_vector_type(8)));
typedef float  f32x4  __attribute__((ext_vector_type(4)));

__device__ __forceinline__ unsigned short f2bf(float f) {
  union { float f; uint32_t u; } v; v.f = f;
  uint32_t u = v.u;
  uint32_t r = (u + 0x7fffu + ((u >> 16) & 1u)) >> 16;
  return (unsigned short)r;
}

__device__ __forceinline__ unsigned int cvt_pk_bf16(float lo, float hi) {
  unsigned int r;
  asm("v_cvt_pk_bf16_f32 %0, %1, %2" : "=v"(r) : "v"(lo), "v"(hi));
  return r;
}

#define GLOAD_LDS16(gsrc, ldst)                                                   \
  __builtin_amdgcn_global_load_lds(                                               \
      (const __attribute__((address_space(1))) void*)(gsrc),                      \
      (__attribute__((address_space(3))) void*)(ldst), 16, 0, 0)

// ---------------- conversion kernels ----------------

__global__ void cvt_x_kernel(const float* __restrict__ in,
                             unsigned short* __restrict__ out, int n4) {
  int i = blockIdx.x * blockDim.x + threadIdx.x;
  int stride = gridDim.x * blockDim.x;
  for (; i < n4; i += stride) {
    float4 f = ((const float4*)in)[i];
    ushort4 o;
    o.x = f2bf(f.x); o.y = f2bf(f.y); o.z = f2bf(f.z); o.w = f2bf(f.w);
    ((ushort4*)out)[i] = o;
  }
}

__global__ void cvt_w_t_kernel(const float* __restrict__ w0,
                               const float* __restrict__ w1,
                               const float* __restrict__ w2,
                               const float* __restrict__ w3,
                               unsigned short* __restrict__ out) {
  __shared__ float tile[32][33];
  const float* src = (blockIdx.z == 0) ? w0 : (blockIdx.z == 1) ? w1
                   : (blockIdx.z == 2) ? w2 : w3;
  unsigned short* dst = out + (size_t)blockIdx.z * (DIN * DOUT);
  int kb = blockIdx.x * 32, nb = blockIdx.y * 32;
  tile[threadIdx.y][threadIdx.x] = src[(size_t)(kb + threadIdx.y) * DOUT + nb + threadIdx.x];
  __syncthreads();
  dst[(size_t)(nb + threadIdx.y) * DIN + kb + threadIdx.x] = f2bf(tile[threadIdx.x][threadIdx.y]);
}

// ---------------- GEMM core: 256x256, 8 waves, BK=64, 8-phase pipeline ------
// LDS 128 KB: A sub-blocks [buf][k2] of 256x32 bf16 at (buf*2+k2)*8192 elems;
// B at +32768. Swizzle within 32-col sub: phys chunk = logical ^ ((row>>1)&3);
// global_load_lds dest linear, source pre-XOR'd (both-sides rule).
// Per K-tile (BK=64): 4 phases x 16 MFMA. Phase A: issue 4 A-hi ds_reads +
// 2 stages, MFMA (compiler's counted lgkm overlaps). Phase B: vmcnt(2)+
// lgkmcnt(0) + raw s_barrier (publish next sub; loads stay in flight), issue
// next half's 8 ds_reads + 2 stages, MFMA. Stages run 1 K-tile ahead.
__device__ __forceinline__ void gemm256_core(const unsigned short* __restrict__ A,
                                             const unsigned short* __restrict__ BT,
                                             f32x4 (&acc)[8][4]) {
  extern __shared__ __align__(16) unsigned short sm[];
  const int tid = threadIdx.x, lane = tid & 63, w = tid >> 6;
  const int wr = w >> 2, wc = w & 3;
  const int g = lane >> 4, c = lane & 15;

#pragma unroll
  for (int mi = 0; mi < 8; mi++)
#pragma unroll
    for (int ni = 0; ni < 4; ni++)
      acc[mi][ni] = (f32x4){0.f, 0.f, 0.f, 0.f};

  // stage sources: thread t -> row t>>2 (+128 call 2), logical chunk pre-XOR'd
  const int srow = tid >> 2;
  const int sl = (tid & 3) ^ ((tid >> 3) & 3);
  const unsigned short* pA0 = A + (size_t)srow * 1024 + sl * 8;
  const unsigned short* pA1 = pA0 + (size_t)128 * 1024;
  const unsigned short* pB0 = BT + (size_t)srow * 1024 + sl * 8;
  const unsigned short* pB1 = pB0 + (size_t)128 * 1024;
  const int dA = tid * 8;   // linear LDS dest (elems): + call*4096 + base

#define AD(B,K) (((B) * 2 + (K)) * 8192)
#define BD(B,K) (32768 + ((B) * 2 + (K)) * 8192)
#define STG_A(OFF, B, K) do {                                   \
    GLOAD_LDS16(pA0 + (OFF), &sm[AD(B,K) + dA]);                \
    GLOAD_LDS16(pA1 + (OFF), &sm[AD(B,K) + 4096 + dA]); } while (0)
#define STG_B(OFF, B, K) do {                                   \
    GLOAD_LDS16(pB0 + (OFF), &sm[BD(B,K) + dA]);                \
    GLOAD_LDS16(pB1 + (OFF), &sm[BD(B,K) + 4096 + dA]); } while (0)

  // fragment read offsets (within a sub-block)
  const int rsw = (c >> 1) & 3;
  int aoff[8], boff[4];
#pragma unroll
  for (int mi = 0; mi < 8; mi++)
    aoff[mi] = (wr * 128 + mi * 16 + c) * 32 + ((g ^ rsw) * 8);
#pragma unroll
  for (int ni = 0; ni < 4; ni++)
    boff[ni] = (wc * 64 + ni * 16 + c) * 32 + ((g ^ rsw) * 8);

#define RD_ALO(B, K, DST) do {                                  \
    DST[0] = *(const bf16x8*)&sm[AD(B,K) + aoff[0]];            \
    DST[1] = *(const bf16x8*)&sm[AD(B,K) + aoff[1]];            \
    DST[2] = *(const bf16x8*)&sm[AD(B,K) + aoff[2]];            \
    DST[3] = *(const bf16x8*)&sm[AD(B,K) + aoff[3]]; } while (0)
#define RD_AHI(B, K, DST) do {                                  \
    DST[0] = *(const bf16x8*)&sm[AD(B,K) + aoff[4]];            \
    DST[1] = *(const bf16x8*)&sm[AD(B,K) + aoff[5]];            \
    DST[2] = *(const bf16x8*)&sm[AD(B,K) + aoff[6]];            \
    DST[3] = *(const bf16x8*)&sm[AD(B,K) + aoff[7]]; } while (0)
#define RD_B(B, K, DST) do {                                    \
    DST[0] = *(const bf16x8*)&sm[BD(B,K) + boff[0]];            \
    DST[1] = *(const bf16x8*)&sm[BD(B,K) + boff[1]];            \
    DST[2] = *(const bf16x8*)&sm[BD(B,K) + boff[2]];            \
    DST[3] = *(const bf16x8*)&sm[BD(B,K) + boff[3]]; } while (0)
#define MM(AS, BS, MB) do {                                     \
    _Pragma("unroll") for (int mi2 = 0; mi2 < 4; ++mi2)         \
    _Pragma("unroll") for (int ni2 = 0; ni2 < 4; ++ni2)         \
      acc[(MB) + mi2][ni2] = __builtin_amdgcn_mfma_f32_16x16x32_bf16( \
          AS[mi2], BS[ni2], acc[(MB) + mi2][ni2], 0, 0, 0); } while (0)
#define SB0 __builtin_amdgcn_sched_barrier(0)
#define P1  __builtin_amdgcn_s_setprio(1)
#define P0  __builtin_amdgcn_s_setprio(0)
#define WAITB(N) do {                                           \
    asm volatile("s_waitcnt vmcnt(" #N ") lgkmcnt(0)" ::: "memory"); \
    __builtin_amdgcn_s_barrier();                               \
    SB0; } while (0)

  // prologue: stage K-tile 0 (both subs); publish sub0; first half's reads
  STG_A(0, 0, 0); STG_B(0, 0, 0); STG_A(32, 0, 1); STG_B(32, 0, 1);
  asm volatile("s_waitcnt vmcnt(4)" ::: "memory");
  __builtin_amdgcn_s_barrier();
  SB0;
  bf16x8 aC[4], aN[4], bCe[4], bCo[4];
  RD_ALO(0, 0, aC); RD_B(0, 0, bCe);

#pragma unroll 1
  for (int i = 0; i < 7; ++i) {   // K-tile pairs (0,1)..(12,13)
    // H0: kt even, buf0, k2=0, bCe
    RD_AHI(0, 0, aN); STG_A(64, 1, 0);
    SB0; P1; MM(aC, bCe, 0); P0;
    WAITB(2);
    RD_ALO(0, 1, aC); RD_B(0, 1, bCo); STG_B(64, 1, 0);
    SB0; P1; MM(aN, bCe, 4); P0;
    // H1: buf0, k2=1, bCo
    RD_AHI(0, 1, aN); STG_A(96, 1, 1);
    SB0; P1; MM(aC, bCo, 0); P0;
    WAITB(2);
    RD_ALO(1, 0, aC); RD_B(1, 0, bCe); STG_B(96, 1, 1);
    SB0; P1; MM(aN, bCo, 4); P0;
    // H2: kt odd, buf1, k2=0, bCe
    RD_AHI(1, 0, aN); STG_A(128, 0, 0);
    SB0; P1; MM(aC, bCe, 0); P0;
    WAITB(2);
    RD_ALO(1, 1, aC); RD_B(1, 1, bCo); STG_B(128, 0, 0);
    SB0; P1; MM(aN, bCe, 4); P0;
    // H3: buf1, k2=1, bCo
    RD_AHI(1, 1, aN); STG_A(160, 0, 1);
    SB0; P1; MM(aC, bCo, 0); P0;
    WAITB(2);
    RD_ALO(0, 0, aC); RD_B(0, 0, bCe); STG_B(160, 0, 1);
    SB0; P1; MM(aN, bCo, 4); P0;
    pA0 += 128; pA1 += 128; pB0 += 128; pB1 += 128;
  }
  // tail: kt=14 (buf0, stages kt15) + kt=15 (buf1, drain)
  RD_AHI(0, 0, aN); STG_A(64, 1, 0);
  SB0; P1; MM(aC, bCe, 0); P0;
  WAITB(2);
  RD_ALO(0, 1, aC); RD_B(0, 1, bCo); STG_B(64, 1, 0);
  SB0; P1; MM(aN, bCe, 4); P0;
  RD_AHI(0, 1, aN); STG_A(96, 1, 1);
  SB0; P1; MM(aC, bCo, 0); P0;
  WAITB(2);
  RD_ALO(1, 0, aC); RD_B(1, 0, bCe); STG_B(96, 1, 1);
  SB0; P1; MM(aN, bCo, 4); P0;
  // kt=15
  RD_AHI(1, 0, aN);
  SB0; P1; MM(aC, bCe, 0); P0;
  WAITB(0);
  RD_ALO(1, 1, aC); RD_B(1, 1, bCo);
  SB0; P1; MM(aN, bCe, 4); P0;
  RD_AHI(1, 1, aN);
  SB0; P1; MM(aC, bCo, 0); P0;
  P1; MM(aN, bCo, 4); P0;

#undef AD
#undef BD
#undef STG_A
#undef STG_B
#undef RD_ALO
#undef RD_AHI
#undef RD_B
#undef MM
#undef SB0
#undef P1
#undef P0
#undef WAITB
}

// QKV projection. z=0: Q (scaled log2e/8) -> [b][h][s][hd]; z=1: K; z=2: V^T [b][h][hd][s]
__global__ __launch_bounds__(512, 2) void gemm_qkv_kernel(
    const unsigned short* __restrict__ xb, const unsigned short* __restrict__ wt,
    unsigned short* __restrict__ qs, unsigned short* __restrict__ kbuf,
    unsigned short* __restrict__ vt) {
  const int nT = blockIdx.x, mT = blockIdx.y, z = blockIdx.z;
  f32x4 acc[8][4];
  gemm256_core(xb + (size_t)mT * 256 * 1024,
               wt + (size_t)z * (DIN * DOUT) + (size_t)nT * 256 * 1024, acc);

  const int tid = threadIdx.x, lane = tid & 63, w = tid >> 6;
  const int wr = w >> 2, wc = w & 3;
  const int g = lane >> 4, c = lane & 15;
  const float scale = (z == 0) ? 0.18033688011112042f : 1.0f;  // (1/8)*log2(e)
  unsigned short* dstQK = (z == 0) ? qs : kbuf;
  const int h = nT * 4 + wc;   // n = nT*256 + wc*64 + ni*16 + c
#pragma unroll
  for (int mi = 0; mi < 8; mi++)
#pragma unroll
    for (int ni = 0; ni < 4; ni++) {
      int hd = ni * 16 + c;
#pragma unroll
      for (int jj = 0; jj < 4; jj++) {
        int m = mT * 256 + wr * 128 + mi * 16 + g * 4 + jj;
        int b = m >> 11, ss = m & 2047;
        unsigned short val = f2bf(acc[mi][ni][jj] * scale);
        if (z < 2)
          dstQK[(((size_t)(b * NH + h)) * SS + ss) * HD + hd] = val;
        else
          vt[(((size_t)(b * NH + h)) * HD + hd) * SS + ss] = val;
      }
    }
}

// Output projection: out = ctx @ Wp + bp (fp32 out)
__global__ __launch_bounds__(512, 2) void gemm_out_kernel(
    const unsigned short* __restrict__ ctx, const unsigned short* __restrict__ wtp,
    const float* __restrict__ bp, float* __restrict__ out) {
  const int nT = blockIdx.x, mT = blockIdx.y;
  f32x4 acc[8][4];
  gemm256_core(ctx + (size_t)mT * 256 * 1024, wtp + (size_t)nT * 256 * 1024, acc);

  const int tid = threadIdx.x, lane = tid & 63, w = tid >> 6;
  const int wr = w >> 2, wc = w & 3;
  const int g = lane >> 4, c = lane & 15;
#pragma unroll
  for (int mi = 0; mi < 8; mi++)
#pragma unroll
    for (int ni = 0; ni < 4; ni++) {
      int n = nT * 256 + wc * 64 + ni * 16 + c;
      float bias = bp[n];
#pragma unroll
      for (int jj = 0; jj < 4; jj++) {
        int m = mT * 256 + wr * 128 + mi * 16 + g * 4 + jj;
        out[(size_t)m * DOUT + n] = acc[mi][ni][jj] + bias;
      }
    }
}

// ---------------- flash attention: 8-wave LDS-shared, balanced pairing -------
// (unchanged from round 4/5 -- passed, ~55 us)
__global__ __launch_bounds__(512) void attn_kernel(
    const unsigned short* __restrict__ qs, const unsigned short* __restrict__ kbuf,
    const unsigned short* __restrict__ vt, unsigned short* __restrict__ ctx) {
  const int pairIdx = blockIdx.x, h = blockIdx.y, b = blockIdx.z;
  const int tid = threadIdx.x, lane = tid & 63, w = tid >> 6;
  const int g = lane >> 4, c = lane & 15;
  const size_t bh = (size_t)(b * NH + h);
  const unsigned short* Q = qs + bh * SS * HD;
  const unsigned short* K = kbuf + bh * SS * HD;
  const unsigned short* V = vt + bh * HD * SS;   // [hd][s]

  __shared__ __align__(16) unsigned short Klds[2][64 * 64];
  __shared__ __align__(16) unsigned short Vlds[2][64 * 64];

  const int srow = tid >> 3, scol = tid & 7;
  const int sK_w = ((srow & 3) << 1) | ((srow >> 4) & 1);
  const int sV_w = ((srow & 3) << 1) | ((srow >> 2) & 1);
  const int kdst = srow * 64 + ((scol ^ sK_w) * 8);
  const int vdst = srow * 64 + ((scol ^ sV_w) * 8);
  const unsigned short* Kg0 = K + (size_t)srow * HD + scol * 8;
  const unsigned short* Vg0 = V + (size_t)srow * SS + scol * 8;

  int kaoff[4][2], vaoff[4][2];
#pragma unroll
  for (int ni = 0; ni < 4; ni++) {
    int r = (c >> 2) * 16 + ni * 4 + (c & 3);
    int s = ((r & 3) << 1) | ((r >> 4) & 1);
#pragma unroll
    for (int kk = 0; kk < 2; kk++)
      kaoff[ni][kk] = r * 64 + (((kk * 4 + g) ^ s) * 8);
  }
#pragma unroll
  for (int nh = 0; nh < 4; nh++) {
    int r = nh * 16 + c;
    int s = ((r & 3) << 1) | ((r >> 2) & 1);
#pragma unroll
    for (int k2 = 0; k2 < 2; k2++)
      vaoff[nh][k2] = r * 64 + (((2 * g + k2) ^ s) * 8);
  }

#pragma unroll 1
  for (int seg = 0; seg < 2; ++seg) {
    const int qtB = (seg == 0) ? (3 - pairIdx + 4) : pairIdx;
    const int q0 = qtB * 256 + w * 32;
    const int nt = 4 * qtB + 4;
    const int ntw = q0 / 64 + 1;

    bf16x8 aq[2][2];
#pragma unroll
    for (int qf = 0; qf < 2; qf++)
#pragma unroll
      for (int kk = 0; kk < 2; kk++)
        aq[qf][kk] = *(const bf16x8*)&Q[(size_t)(q0 + qf * 16 + c) * HD + kk * 32 + g * 8];

    float m_run[2] = {-3.0e38f, -3.0e38f};
    float l_run[2] = {0.f, 0.f};
    f32x4 acc[2][4];
#pragma unroll
    for (int qf = 0; qf < 2; qf++)
#pragma unroll
      for (int nh = 0; nh < 4; nh++) acc[qf][nh] = (f32x4){0.f, 0.f, 0.f, 0.f};

    {
      uint4 k0 = *(const uint4*)Kg0;
      uint4 v0 = *(const uint4*)Vg0;
      __syncthreads();
      *(uint4*)&Klds[0][kdst] = k0;
      *(uint4*)&Vlds[0][vdst] = v0;
      __syncthreads();
    }
    int cur = 0;

#pragma unroll 1
    for (int t = 0; t < nt; ++t) {
      const bool more = (t + 1 < nt);
      uint4 knx, vnx;
      if (more) {
        knx = *(const uint4*)(Kg0 + (size_t)(t + 1) * 64 * HD);
        vnx = *(const uint4*)(Vg0 + (size_t)(t + 1) * 64);
      }
      if (t < ntw) {
        const unsigned short* Kl = Klds[cur];
        const unsigned short* Vl = Vlds[cur];
        bf16x8 ka[4][2], va[4][2];
#pragma unroll
        for (int ni = 0; ni < 4; ni++)
#pragma unroll
          for (int kk = 0; kk < 2; kk++)
            ka[ni][kk] = *(const bf16x8*)&Kl[kaoff[ni][kk]];
#pragma unroll
        for (int nh = 0; nh < 4; nh++)
#pragma unroll
          for (int k2 = 0; k2 < 2; k2++)
            va[nh][k2] = *(const bf16x8*)&Vl[vaoff[nh][k2]];

        f32x4 sv[2][4];
        __builtin_amdgcn_s_setprio(1);
#pragma unroll
        for (int qf = 0; qf < 2; qf++)
#pragma unroll
          for (int ni = 0; ni < 4; ni++) {
            f32x4 z = (f32x4){0.f, 0.f, 0.f, 0.f};
            z = __builtin_amdgcn_mfma_f32_16x16x32_bf16(ka[ni][0], aq[qf][0], z, 0, 0, 0);
            sv[qf][ni] = __builtin_amdgcn_mfma_f32_16x16x32_bf16(ka[ni][1], aq[qf][1], z, 0, 0, 0);
          }
        __builtin_amdgcn_s_setprio(0);

        if (t == ntw - 1) {
#pragma unroll
          for (int qf = 0; qf < 2; qf++) {
            int q = q0 + qf * 16 + c;
#pragma unroll
            for (int ni = 0; ni < 4; ni++)
#pragma unroll
              for (int jj = 0; jj < 4; jj++) {
                int kvv = t * 64 + g * 16 + ni * 4 + jj;
                if (kvv > q) sv[qf][ni][jj] = -3.0e38f;
              }
          }
        }

#pragma unroll
        for (int qf = 0; qf < 2; qf++) {
          float mx = sv[qf][0][0];
#pragma unroll
          for (int ni = 0; ni < 4; ni++)
#pragma unroll
            for (int jj = 0; jj < 4; jj++) mx = fmaxf(mx, sv[qf][ni][jj]);
          mx = fmaxf(mx, __shfl_xor(mx, 16));
          mx = fmaxf(mx, __shfl_xor(mx, 32));
          float mnew = fmaxf(m_run[qf], mx);
          float al = exp2f(m_run[qf] - mnew);
          m_run[qf] = mnew;
          float rs = 0.f;
#pragma unroll
          for (int ni = 0; ni < 4; ni++)
#pragma unroll
            for (int jj = 0; jj < 4; jj++) {
              float p = exp2f(sv[qf][ni][jj] - mnew);
              sv[qf][ni][jj] = p;
              rs += p;
            }
          rs += __shfl_xor(rs, 16);
          rs += __shfl_xor(rs, 32);
          l_run[qf] = l_run[qf] * al + rs;
#pragma unroll
          for (int nh = 0; nh < 4; nh++) acc[qf][nh] *= al;

          union { unsigned int u[4]; bf16x8 v; } pb0, pb1;
          pb0.u[0] = cvt_pk_bf16(sv[qf][0][0], sv[qf][0][1]);
          pb0.u[1] = cvt_pk_bf16(sv[qf][0][2], sv[qf][0][3]);
          pb0.u[2] = cvt_pk_bf16(sv[qf][1][0], sv[qf][1][1]);
          pb0.u[3] = cvt_pk_bf16(sv[qf][1][2], sv[qf][1][3]);
          pb1.u[0] = cvt_pk_bf16(sv[qf][2][0], sv[qf][2][1]);
          pb1.u[1] = cvt_pk_bf16(sv[qf][2][2], sv[qf][2][3]);
          pb1.u[2] = cvt_pk_bf16(sv[qf][3][0], sv[qf][3][1]);
          pb1.u[3] = cvt_pk_bf16(sv[qf][3][2], sv[qf][3][3]);

          __builtin_amdgcn_s_setprio(1);
#pragma unroll
          for (int nh = 0; nh < 4; nh++) {
            acc[qf][nh] = __builtin_amdgcn_mfma_f32_16x16x32_bf16(va[nh][0], pb0.v, acc[qf][nh], 0, 0, 0);
            acc[qf][nh] = __builtin_amdgcn_mfma_f32_16x16x32_bf16(va[nh][1], pb1.v, acc[qf][nh], 0, 0, 0);
          }
          __builtin_amdgcn_s_setprio(0);
        }
      }
      if (more) {
        *(uint4*)&Klds[cur ^ 1][kdst] = knx;
        *(uint4*)&Vlds[cur ^ 1][vdst] = vnx;
        __syncthreads();
        cur ^= 1;
      }
    }

#pragma unroll
    for (int qf = 0; qf < 2; qf++) {
      float inv = 1.0f / l_run[qf];
      size_t rowoff = ((size_t)b * SS + q0 + qf * 16 + c) * DOUT + h * HD;
#pragma unroll
      for (int nh = 0; nh < 4; nh++) {
        uint2 st;
        st.x = cvt_pk_bf16(acc[qf][nh][0] * inv, acc[qf][nh][1] * inv);
        st.y = cvt_pk_bf16(acc[qf][nh][2] * inv, acc[qf][nh][3] * inv);
        *(uint2*)&ctx[rowoff + nh * 16 + g * 4] = st;
      }
    }
  }
}

// ---------------- launch ----------------

extern "C" void kernel_launch(void* const* d_in, const int* in_sizes, int n_in,
                              void* d_out, int out_size, void* d_ws, size_t ws_size,
                              hipStream_t stream) {
  const float* x  = (const float*)d_in[0];
  const float* Wq = (const float*)d_in[1];
  const float* Wk = (const float*)d_in[2];
  const float* Wv = (const float*)d_in[3];
  const float* Wp = (const float*)d_in[4];
  const float* bp = (const float*)d_in[5];
  float* out = (float*)d_out;

  unsigned short* ws = (unsigned short*)d_ws;
  unsigned short* xb = ws;                      // 8388608 elems (x bf16; later reused as ctx)
  unsigned short* wt = xb + (size_t)MROWS * DIN;       // 4 * 1048576 (Wq^T,Wk^T,Wv^T,Wp^T)
  unsigned short* qs = wt + (size_t)4 * DIN * DOUT;    // 8388608 (Q scaled, [b][h][s][hd])
  unsigned short* kb = qs + (size_t)MROWS * DOUT;      // 8388608 ([b][h][s][hd])
  unsigned short* vt = kb + (size_t)MROWS * DOUT;      // 8388608 ([b][h][hd][s])
  unsigned short* ctx = xb;                            // alias: x dead after projections

  const int kLds = 128 * 1024;   // double-buffered BK=64 for the 256^2 cores
  (void)hipFuncSetAttribute((const void*)gemm_qkv_kernel,
                            hipFuncAttributeMaxDynamicSharedMemorySize, kLds);
  (void)hipFuncSetAttribute((const void*)gemm_out_kernel,
                            hipFuncAttributeMaxDynamicSharedMemorySize, kLds);

  cvt_x_kernel<<<4096, 256, 0, stream>>>(x, xb, (MROWS * DIN) / 4);
  cvt_w_t_kernel<<<dim3(32, 32, 4), dim3(32, 32), 0, stream>>>(Wq, Wk, Wv, Wp, wt);
  gemm_qkv_kernel<<<dim3(4, 32, 3), 512, kLds, stream>>>(xb, wt, qs, kb, vt);
  attn_kernel<<<dim3(4, NH, BB), 512, 0, stream>>>(qs, kb, vt, ctx);
  gemm_out_kernel<<<dim3(4, 32), 512, kLds, stream>>>(ctx, wt + (size_t)3 * DIN * DOUT, bp, out);
}

// Round 8
// 194.571 us; speedup vs baseline: 1.1180x; 1.0816x over previous
//
#include <hip/hip_runtime.h>
#include <hip/hip_bf16.h>
#include <stdint.h>

// Problem constants
#define BB   4
#define SS   2048
#define DIN  1024
#define DOUT 1024
#define NH   16
#define HD   64
#define MROWS (BB * SS)   // 8192

typedef __bf16 bf16x8 __attribute__((ext_vector_type(8)));
typedef float  f32x4  __attribute__((ext_vector_type(4)));

__device__ __forceinline__ unsigned short f2bf(float f) {
  union { float f; uint32_t u; } v; v.f = f;
  uint32_t u = v.u;
  uint32_t r = (u + 0x7fffu + ((u >> 16) & 1u)) >> 16;
  return (unsigned short)r;
}

__device__ __forceinline__ unsigned int cvt_pk_bf16(float lo, float hi) {
  unsigned int r;
  asm("v_cvt_pk_bf16_f32 %0, %1, %2" : "=v"(r) : "v"(lo), "v"(hi));
  return r;
}

#define GLOAD_LDS16(gsrc, ldst)                                                   \
  __builtin_amdgcn_global_load_lds(                                               \
      (const __attribute__((address_space(1))) void*)(gsrc),                      \
      (__attribute__((address_space(3))) void*)(ldst), 16, 0, 0)

// ---------------- conversion kernels ----------------

__global__ void cvt_x_kernel(const float* __restrict__ in,
                             unsigned short* __restrict__ out, int n4) {
  int i = blockIdx.x * blockDim.x + threadIdx.x;
  int stride = gridDim.x * blockDim.x;
  for (; i < n4; i += stride) {
    float4 f = ((const float4*)in)[i];
    ushort4 o;
    o.x = f2bf(f.x); o.y = f2bf(f.y); o.z = f2bf(f.z); o.w = f2bf(f.w);
    ((ushort4*)out)[i] = o;
  }
}

__global__ void cvt_w_t_kernel(const float* __restrict__ w0,
                               const float* __restrict__ w1,
                               const float* __restrict__ w2,
                               const float* __restrict__ w3,
                               unsigned short* __restrict__ out) {
  __shared__ float tile[32][33];
  const float* src = (blockIdx.z == 0) ? w0 : (blockIdx.z == 1) ? w1
                   : (blockIdx.z == 2) ? w2 : w3;
  unsigned short* dst = out + (size_t)blockIdx.z * (DIN * DOUT);
  int kb = blockIdx.x * 32, nb = blockIdx.y * 32;
  tile[threadIdx.y][threadIdx.x] = src[(size_t)(kb + threadIdx.y) * DOUT + nb + threadIdx.x];
  __syncthreads();
  dst[(size_t)(nb + threadIdx.y) * DIN + kb + threadIdx.x] = f2bf(tile[threadIdx.x][threadIdx.y]);
}

// ---------------- GEMM core: 128x128 tile, BK=64, dbuf 64KB, 2 blocks/CU ----
// The pipelining mechanism here is CO-RESIDENCY (2 blocks/CU overlap each
// other's stage/drain windows), not in-kernel asm scheduling. Simple loop:
// STAGE(t+1) first (max lead), ds_read + 32 MFMA, one __syncthreads (drains).
// LDS [2][128x64] per matrix; swizzle: phys chunk = chunk ^ (row&7), applied
// on ds_read and pre-applied on the global SOURCE (dest stays linear, rule 21).
__device__ __forceinline__ void gemm128_core(const unsigned short* __restrict__ A,
                                             const unsigned short* __restrict__ BT,
                                             f32x4 (&acc)[4][4]) {
  extern __shared__ __align__(16) unsigned short sm[];
  // As buf b at b*8192; Bs at 16384 + b*8192  (elems; 64 KB total)
  const int tid = threadIdx.x, lane = tid & 63, w = tid >> 6;
  const int wm = (w >> 1) * 64, wn = (w & 1) * 64;
  const int g = lane >> 4, c = lane & 15;

#pragma unroll
  for (int mi = 0; mi < 4; mi++)
#pragma unroll
    for (int ni = 0; ni < 4; ni++)
      acc[mi][ni] = (f32x4){0.f, 0.f, 0.f, 0.f};

  // staging: 4 calls/matrix/tile; call j covers rows j*32..+31.
  // thread -> row (tid>>3), chunk (tid&7); global chunk pre-XOR'd by row&7.
  const int srow = tid >> 3;
  const int gchunk = (tid & 7) ^ (srow & 7);
  const unsigned short* Ag = A + (size_t)srow * 1024 + gchunk * 8;
  const unsigned short* Bg = BT + (size_t)srow * 1024 + gchunk * 8;
  const int dst8 = tid * 8;   // + j*2048 : linear LDS dest (elems)

#define STAGE128(kt, buf) do {                                              \
    const int _k = (kt) * 64;                                               \
    _Pragma("unroll") for (int _j = 0; _j < 4; ++_j) {                      \
      GLOAD_LDS16(Ag + (size_t)_j * 32 * 1024 + _k,                         \
                  &sm[(buf) * 8192 + _j * 2048 + dst8]);                    \
      GLOAD_LDS16(Bg + (size_t)_j * 32 * 1024 + _k,                         \
                  &sm[16384 + (buf) * 8192 + _j * 2048 + dst8]);            \
    } } while (0)

  // fragment read offsets: row r, chunk (k2*4+g) ^ (c&7)  [r&7 == c&7]
  int aoff[4][2], boff[4][2];
#pragma unroll
  for (int mi = 0; mi < 4; mi++)
#pragma unroll
    for (int k2 = 0; k2 < 2; k2++)
      aoff[mi][k2] = (wm + mi * 16 + c) * 64 + (((k2 * 4 + g) ^ (c & 7)) * 8);
#pragma unroll
  for (int ni = 0; ni < 4; ni++)
#pragma unroll
    for (int k2 = 0; k2 < 2; k2++)
      boff[ni][k2] = (wn + ni * 16 + c) * 64 + (((k2 * 4 + g) ^ (c & 7)) * 8);

  STAGE128(0, 0);
  __syncthreads();   // tile 0 resident

#pragma unroll 1
  for (int t = 0; t < 16; ++t) {
    const int buf = t & 1;
    if (t + 1 < 16) STAGE128(t + 1, buf ^ 1);   // issued first: max lead time
    const unsigned short* As_ = sm + buf * 8192;
    const unsigned short* Bs_ = sm + 16384 + buf * 8192;
#pragma unroll
    for (int k2 = 0; k2 < 2; k2++) {
      bf16x8 a[4], b[4];
#pragma unroll
      for (int mi = 0; mi < 4; mi++) a[mi] = *(const bf16x8*)&As_[aoff[mi][k2]];
#pragma unroll
      for (int ni = 0; ni < 4; ni++) b[ni] = *(const bf16x8*)&Bs_[boff[ni][k2]];
#pragma unroll
      for (int mi = 0; mi < 4; mi++)
#pragma unroll
        for (int ni = 0; ni < 4; ni++)
          acc[mi][ni] = __builtin_amdgcn_mfma_f32_16x16x32_bf16(a[mi], b[ni], acc[mi][ni], 0, 0, 0);
    }
    __syncthreads();   // drains vmcnt+lgkm: tile t+1 resident, readers done
  }
#undef STAGE128
}

// QKV projection. z=0: Q (scaled log2e/8) -> [b][h][s][hd]; z=1: K; z=2: V^T [b][h][hd][s]
__global__ __launch_bounds__(256, 2) void gemm_qkv_kernel(
    const unsigned short* __restrict__ xb, const unsigned short* __restrict__ wt,
    unsigned short* __restrict__ qs, unsigned short* __restrict__ kbuf,
    unsigned short* __restrict__ vt) {
  const int nT = blockIdx.x, mT = blockIdx.y, z = blockIdx.z;
  f32x4 acc[4][4];
  gemm128_core(xb + (size_t)mT * 128 * 1024,
               wt + (size_t)z * (DIN * DOUT) + (size_t)nT * 128 * 1024, acc);

  const int tid = threadIdx.x, lane = tid & 63, w = tid >> 6;
  const int wm = (w >> 1) * 64, wn = (w & 1) * 64;
  const int g = lane >> 4, c = lane & 15;
  const float scale = (z == 0) ? 0.18033688011112042f : 1.0f;  // (1/8)*log2(e)

  if (z < 2) {
    unsigned short* dstQK = (z == 0) ? qs : kbuf;
#pragma unroll
    for (int mi = 0; mi < 4; mi++)
#pragma unroll
      for (int ni = 0; ni < 4; ni++) {
        int n = nT * 128 + wn + ni * 16 + c;
        int h = n >> 6, hd = n & 63;
#pragma unroll
        for (int jj = 0; jj < 4; jj++) {
          int m = mT * 128 + wm + mi * 16 + g * 4 + jj;
          int b = m >> 11, ss = m & 2047;
          dstQK[(((size_t)(b * NH + h)) * SS + ss) * HD + hd] = f2bf(acc[mi][ni][jj] * scale);
        }
      }
  } else {
    // V^T: per (mi,ni) the 4 jj values are 4 consecutive s -> one uint2 store
#pragma unroll
    for (int mi = 0; mi < 4; mi++) {
      int m0 = mT * 128 + wm + mi * 16 + g * 4;
      int b = m0 >> 11, s0 = m0 & 2047;
#pragma unroll
      for (int ni = 0; ni < 4; ni++) {
        int n = nT * 128 + wn + ni * 16 + c;
        int h = n >> 6, hd = n & 63;
        uint2 st;
        st.x = cvt_pk_bf16(acc[mi][ni][0], acc[mi][ni][1]);
        st.y = cvt_pk_bf16(acc[mi][ni][2], acc[mi][ni][3]);
        *(uint2*)&vt[(((size_t)(b * NH + h)) * HD + hd) * SS + s0] = st;
      }
    }
  }
}

// Output projection: out = ctx @ Wp + bp (fp32 out)
__global__ __launch_bounds__(256, 2) void gemm_out_kernel(
    const unsigned short* __restrict__ ctx, const unsigned short* __restrict__ wtp,
    const float* __restrict__ bp, float* __restrict__ out) {
  const int nT = blockIdx.x, mT = blockIdx.y;
  f32x4 acc[4][4];
  gemm128_core(ctx + (size_t)mT * 128 * 1024, wtp + (size_t)nT * 128 * 1024, acc);

  const int tid = threadIdx.x, lane = tid & 63, w = tid >> 6;
  const int wm = (w >> 1) * 64, wn = (w & 1) * 64;
  const int g = lane >> 4, c = lane & 15;
#pragma unroll
  for (int mi = 0; mi < 4; mi++)
#pragma unroll
    for (int ni = 0; ni < 4; ni++) {
      int n = nT * 128 + wn + ni * 16 + c;
      float bias = bp[n];
#pragma unroll
      for (int jj = 0; jj < 4; jj++) {
        int m = mT * 128 + wm + mi * 16 + g * 4 + jj;
        out[(size_t)m * DOUT + n] = acc[mi][ni][jj] + bias;
      }
    }
}

// ---------------- flash attention: 8-wave LDS-shared, balanced pairing -------
// (unchanged from round 4 -- ~55 us)
__global__ __launch_bounds__(512) void attn_kernel(
    const unsigned short* __restrict__ qs, const unsigned short* __restrict__ kbuf,
    const unsigned short* __restrict__ vt, unsigned short* __restrict__ ctx) {
  const int pairIdx = blockIdx.x, h = blockIdx.y, b = blockIdx.z;
  const int tid = threadIdx.x, lane = tid & 63, w = tid >> 6;
  const int g = lane >> 4, c = lane & 15;
  const size_t bh = (size_t)(b * NH + h);
  const unsigned short* Q = qs + bh * SS * HD;
  const unsigned short* K = kbuf + bh * SS * HD;
  const unsigned short* V = vt + bh * HD * SS;   // [hd][s]

  __shared__ __align__(16) unsigned short Klds[2][64 * 64];
  __shared__ __align__(16) unsigned short Vlds[2][64 * 64];

  const int srow = tid >> 3, scol = tid & 7;
  const int sK_w = ((srow & 3) << 1) | ((srow >> 4) & 1);
  const int sV_w = ((srow & 3) << 1) | ((srow >> 2) & 1);
  const int kdst = srow * 64 + ((scol ^ sK_w) * 8);
  const int vdst = srow * 64 + ((scol ^ sV_w) * 8);
  const unsigned short* Kg0 = K + (size_t)srow * HD + scol * 8;
  const unsigned short* Vg0 = V + (size_t)srow * SS + scol * 8;

  int kaoff[4][2], vaoff[4][2];
#pragma unroll
  for (int ni = 0; ni < 4; ni++) {
    int r = (c >> 2) * 16 + ni * 4 + (c & 3);
    int s = ((r & 3) << 1) | ((r >> 4) & 1);
#pragma unroll
    for (int kk = 0; kk < 2; kk++)
      kaoff[ni][kk] = r * 64 + (((kk * 4 + g) ^ s) * 8);
  }
#pragma unroll
  for (int nh = 0; nh < 4; nh++) {
    int r = nh * 16 + c;
    int s = ((r & 3) << 1) | ((r >> 2) & 1);
#pragma unroll
    for (int k2 = 0; k2 < 2; k2++)
      vaoff[nh][k2] = r * 64 + (((2 * g + k2) ^ s) * 8);
  }

#pragma unroll 1
  for (int seg = 0; seg < 2; ++seg) {
    const int qtB = (seg == 0) ? (3 - pairIdx + 4) : pairIdx;
    const int q0 = qtB * 256 + w * 32;
    const int nt = 4 * qtB + 4;
    const int ntw = q0 / 64 + 1;

    bf16x8 aq[2][2];
#pragma unroll
    for (int qf = 0; qf < 2; qf++)
#pragma unroll
      for (int kk = 0; kk < 2; kk++)
        aq[qf][kk] = *(const bf16x8*)&Q[(size_t)(q0 + qf * 16 + c) * HD + kk * 32 + g * 8];

    float m_run[2] = {-3.0e38f, -3.0e38f};
    float l_run[2] = {0.f, 0.f};
    f32x4 acc[2][4];
#pragma unroll
    for (int qf = 0; qf < 2; qf++)
#pragma unroll
      for (int nh = 0; nh < 4; nh++) acc[qf][nh] = (f32x4){0.f, 0.f, 0.f, 0.f};

    {
      uint4 k0 = *(const uint4*)Kg0;
      uint4 v0 = *(const uint4*)Vg0;
      __syncthreads();
      *(uint4*)&Klds[0][kdst] = k0;
      *(uint4*)&Vlds[0][vdst] = v0;
      __syncthreads();
    }
    int cur = 0;

#pragma unroll 1
    for (int t = 0; t < nt; ++t) {
      const bool more = (t + 1 < nt);
      uint4 knx, vnx;
      if (more) {
        knx = *(const uint4*)(Kg0 + (size_t)(t + 1) * 64 * HD);
        vnx = *(const uint4*)(Vg0 + (size_t)(t + 1) * 64);
      }
      if (t < ntw) {
        const unsigned short* Kl = Klds[cur];
        const unsigned short* Vl = Vlds[cur];
        bf16x8 ka[4][2], va[4][2];
#pragma unroll
        for (int ni = 0; ni < 4; ni++)
#pragma unroll
          for (int kk = 0; kk < 2; kk++)
            ka[ni][kk] = *(const bf16x8*)&Kl[kaoff[ni][kk]];
#pragma unroll
        for (int nh = 0; nh < 4; nh++)
#pragma unroll
          for (int k2 = 0; k2 < 2; k2++)
            va[nh][k2] = *(const bf16x8*)&Vl[vaoff[nh][k2]];

        f32x4 sv[2][4];
        __builtin_amdgcn_s_setprio(1);
#pragma unroll
        for (int qf = 0; qf < 2; qf++)
#pragma unroll
          for (int ni = 0; ni < 4; ni++) {
            f32x4 z = (f32x4){0.f, 0.f, 0.f, 0.f};
            z = __builtin_amdgcn_mfma_f32_16x16x32_bf16(ka[ni][0], aq[qf][0], z, 0, 0, 0);
            sv[qf][ni] = __builtin_amdgcn_mfma_f32_16x16x32_bf16(ka[ni][1], aq[qf][1], z, 0, 0, 0);
          }
        __builtin_amdgcn_s_setprio(0);

        if (t == ntw - 1) {
#pragma unroll
          for (int qf = 0; qf < 2; qf++) {
            int q = q0 + qf * 16 + c;
#pragma unroll
            for (int ni = 0; ni < 4; ni++)
#pragma unroll
              for (int jj = 0; jj < 4; jj++) {
                int kvv = t * 64 + g * 16 + ni * 4 + jj;
                if (kvv > q) sv[qf][ni][jj] = -3.0e38f;
              }
          }
        }

#pragma unroll
        for (int qf = 0; qf < 2; qf++) {
          float mx = sv[qf][0][0];
#pragma unroll
          for (int ni = 0; ni < 4; ni++)
#pragma unroll
            for (int jj = 0; jj < 4; jj++) mx = fmaxf(mx, sv[qf][ni][jj]);
          mx = fmaxf(mx, __shfl_xor(mx, 16));
          mx = fmaxf(mx, __shfl_xor(mx, 32));
          float mnew = fmaxf(m_run[qf], mx);
          float al = exp2f(m_run[qf] - mnew);
          m_run[qf] = mnew;
          float rs = 0.f;
#pragma unroll
          for (int ni = 0; ni < 4; ni++)
#pragma unroll
            for (int jj = 0; jj < 4; jj++) {
              float p = exp2f(sv[qf][ni][jj] - mnew);
              sv[qf][ni][jj] = p;
              rs += p;
            }
          rs += __shfl_xor(rs, 16);
          rs += __shfl_xor(rs, 32);
          l_run[qf] = l_run[qf] * al + rs;
#pragma unroll
          for (int nh = 0; nh < 4; nh++) acc[qf][nh] *= al;

          union { unsigned int u[4]; bf16x8 v; } pb0, pb1;
          pb0.u[0] = cvt_pk_bf16(sv[qf][0][0], sv[qf][0][1]);
          pb0.u[1] = cvt_pk_bf16(sv[qf][0][2], sv[qf][0][3]);
          pb0.u[2] = cvt_pk_bf16(sv[qf][1][0], sv[qf][1][1]);
          pb0.u[3] = cvt_pk_bf16(sv[qf][1][2], sv[qf][1][3]);
          pb1.u[0] = cvt_pk_bf16(sv[qf][2][0], sv[qf][2][1]);
          pb1.u[1] = cvt_pk_bf16(sv[qf][2][2], sv[qf][2][3]);
          pb1.u[2] = cvt_pk_bf16(sv[qf][3][0], sv[qf][3][1]);
          pb1.u[3] = cvt_pk_bf16(sv[qf][3][2], sv[qf][3][3]);

          __builtin_amdgcn_s_setprio(1);
#pragma unroll
          for (int nh = 0; nh < 4; nh++) {
            acc[qf][nh] = __builtin_amdgcn_mfma_f32_16x16x32_bf16(va[nh][0], pb0.v, acc[qf][nh], 0, 0, 0);
            acc[qf][nh] = __builtin_amdgcn_mfma_f32_16x16x32_bf16(va[nh][1], pb1.v, acc[qf][nh], 0, 0, 0);
          }
          __builtin_amdgcn_s_setprio(0);
        }
      }
      if (more) {
        *(uint4*)&Klds[cur ^ 1][kdst] = knx;
        *(uint4*)&Vlds[cur ^ 1][vdst] = vnx;
        __syncthreads();
        cur ^= 1;
      }
    }

#pragma unroll
    for (int qf = 0; qf < 2; qf++) {
      float inv = 1.0f / l_run[qf];
      size_t rowoff = ((size_t)b * SS + q0 + qf * 16 + c) * DOUT + h * HD;
#pragma unroll
      for (int nh = 0; nh < 4; nh++) {
        uint2 st;
        st.x = cvt_pk_bf16(acc[qf][nh][0] * inv, acc[qf][nh][1] * inv);
        st.y = cvt_pk_bf16(acc[qf][nh][2] * inv, acc[qf][nh][3] * inv);
        *(uint2*)&ctx[rowoff + nh * 16 + g * 4] = st;
      }
    }
  }
}

// ---------------- launch ----------------

extern "C" void kernel_launch(void* const* d_in, const int* in_sizes, int n_in,
                              void* d_out, int out_size, void* d_ws, size_t ws_size,
                              hipStream_t stream) {
  const float* x  = (const float*)d_in[0];
  const float* Wq = (const float*)d_in[1];
  const float* Wk = (const float*)d_in[2];
  const float* Wv = (const float*)d_in[3];
  const float* Wp = (const float*)d_in[4];
  const float* bp = (const float*)d_in[5];
  float* out = (float*)d_out;

  unsigned short* ws = (unsigned short*)d_ws;
  unsigned short* xb = ws;                      // 8388608 elems (x bf16; later reused as ctx)
  unsigned short* wt = xb + (size_t)MROWS * DIN;       // 4 * 1048576 (Wq^T,Wk^T,Wv^T,Wp^T)
  unsigned short* qs = wt + (size_t)4 * DIN * DOUT;    // 8388608 (Q scaled, [b][h][s][hd])
  unsigned short* kb = qs + (size_t)MROWS * DOUT;      // 8388608 ([b][h][s][hd])
  unsigned short* vt = kb + (size_t)MROWS * DOUT;      // 8388608 ([b][h][hd][s])
  unsigned short* ctx = xb;                            // alias: x dead after projections

  const int kLds = 64 * 1024;   // BK=64 double-buffer -> 2 blocks/CU
  (void)hipFuncSetAttribute((const void*)gemm_qkv_kernel,
                            hipFuncAttributeMaxDynamicSharedMemorySize, kLds);
  (void)hipFuncSetAttribute((const void*)gemm_out_kernel,
                            hipFuncAttributeMaxDynamicSharedMemorySize, kLds);

  cvt_x_kernel<<<4096, 256, 0, stream>>>(x, xb, (MROWS * DIN) / 4);
  cvt_w_t_kernel<<<dim3(32, 32, 4), dim3(32, 32), 0, stream>>>(Wq, Wk, Wv, Wp, wt);
  gemm_qkv_kernel<<<dim3(8, 64, 3), 256, kLds, stream>>>(xb, wt, qs, kb, vt);
  attn_kernel<<<dim3(4, NH, BB), 512, 0, stream>>>(qs, kb, vt, ctx);
  gemm_out_kernel<<<dim3(8, 64), 256, kLds, stream>>>(ctx, wt + (size_t)3 * DIN * DOUT, bp, out);
}